// Round 12
// baseline (227.210 us; speedup 1.0000x reference)
//
#include <hip/hip_runtime.h>

#define N_NODES 100000
#define N_EDGES 1250000
#define D 64
#define ZERO_NODE N_NODES       // virtual all-zero row for padding

// bins == fused blocks: 32 nodes per bin, 3125 bins (100000/32 exactly)
#define BSHIFT 5
#define BINSZ 32
#define NBIN (N_NODES / BINSZ)                 // 3125
#define CH 4096                                // edges per partition block
#define NC ((N_EDGES + CH - 1) / CH)           // 306
#define CAP 16                                 // slots/cell = 64B = 1 line; Poisson(1.31), P(>16)~1e-12
#define CONV4 (N_NODES * D / 4)                // 1,600,000 float4s to convert

#define RAWCAP 704      // staged raw edges per bin (Poisson(400), +8 sigma = 560)
#define ELCAP 832       // padded per-row lists (raw + 3*32 pad worst case)

typedef __attribute__((ext_vector_type(8))) short short8;   // 8 bf16 (4 VGPRs)
typedef __attribute__((ext_vector_type(4))) float f32x4;    // MFMA acc

// ---- bf16 helpers (finite values only) ----
__device__ inline unsigned short f2bf(float f) {
    unsigned int u = __float_as_uint(f);
    unsigned int r = (u + 0x7fffu + ((u >> 16) & 1u)) >> 16;
    return (unsigned short)r;
}
__device__ inline void acc_bf4(float4& c, uint2 u) {
    c.x += __uint_as_float(u.x << 16);
    c.y += __uint_as_float(u.x & 0xffff0000u);
    c.z += __uint_as_float(u.y << 16);
    c.w += __uint_as_float(u.y & 0xffff0000u);
}

// ---- pass 1 (merged convert + partition): deterministic per-(bin,chunk) cells ----
// 306 blocks x 1024 threads, single pass over the chunk's edges: rank from a
// block-local LDS cursor, edge -> cslab[bin][chunk][rank] (cell = 64B line).
// Per-bin data contiguous for the fused consumer. No global atomics, no scans,
// no second pass. Convert (fp32->bf16), zero-rows, wt transpose ride along.
__global__ __launch_bounds__(1024)
void part_convert_kernel(const float4* __restrict__ xin, ushort4* __restrict__ xb,
                         unsigned int* __restrict__ xb_zrow,
                         unsigned int* __restrict__ h_zrow,
                         const float* __restrict__ Wl1, const float* __restrict__ Wr1,
                         const float* __restrict__ Wl2, const float* __restrict__ Wr2,
                         unsigned short* __restrict__ wt,
                         const int* __restrict__ src, const int* __restrict__ dst,
                         int* __restrict__ cslab, unsigned char* __restrict__ ccnt) {
    __shared__ int lcur[NBIN];   // 3125 ints = 12.5 KB

    const int t = threadIdx.x;
    const int c = blockIdx.x;
    for (int i = t; i < NBIN; i += 1024) lcur[i] = 0;

    // convert x fp32 -> bf16 (grid-stride) + one-time extras
    const int g0 = c * 1024 + t;
    const int gsz = NC * 1024;   // 313,344
    for (int g = g0; g < CONV4; g += gsz) {
        float4 v = xin[g];
        ushort4 u;
        u.x = f2bf(v.x); u.y = f2bf(v.y); u.z = f2bf(v.z); u.w = f2bf(v.w);
        xb[g] = u;
    }
    if (g0 < 32) { xb_zrow[g0] = 0u; h_zrow[g0] = 0u; }   // 64 bf16 = 32 uints each
    if (g0 < 2 * 64 * 128) {
        int layer = g0 >> 13;
        int n = (g0 >> 7) & 63;
        int k = g0 & 127;
        const float* W = layer ? (k < 64 ? Wl2 : Wr2) : (k < 64 ? Wl1 : Wr1);
        wt[g0] = f2bf(W[(k & 63) * D + n]);
    }
    __syncthreads();

    const int e0 = c * CH;
    int cnt = N_EDGES - e0; if (cnt > CH) cnt = CH;
    for (int i = t; i < cnt; i += 1024) {
        int d = dst[e0 + i];
        int s = src[e0 + i];
        int b = d >> BSHIFT;
        int r = atomicAdd(&lcur[b], 1);
        if (r < CAP)
            cslab[((size_t)b * NC + c) * CAP + r] = (s << BSHIFT) | (d & (BINSZ - 1));
    }
    __syncthreads();

    for (int i = t; i < NBIN; i += 1024) {
        int v = lcur[i];
        ccnt[(size_t)i * NC + c] = (unsigned char)(v < CAP ? v : CAP);
    }
}

// ---------------- fused layer: LDS mini-build + gather-mean + MFMA GEMM --------
// Mini-build: block b reads ITS bin's cells (NC*CAP ints, contiguous, validity-
// guarded), compacts -> raw[], 32-entry hist + shfl scan -> per-row padded edge
// lists in LDS elist[]. Replaces the global CSR build kernel entirely; gather's
// idx loads become LDS reads (one fewer dependent global load in the chain).
// Gather: quad-edge (uint2/lane, 16 lanes/row), 4 rows per wave iteration,
// launch_bounds(256,6) (85-VGPR budget, no spill -- r10 measured VGPR=40).
// GEMM: C[32,64] = [mean|x]_bf16[32,128] @ wt[128,64] + b  via
// mfma_f32_16x16x32_bf16 (8 tiles, 4 waves x 2 tiles x 4 K-steps).
template <typename TOUT>
__global__ __launch_bounds__(256, 6)
void fused_layer_kernel(const unsigned short* __restrict__ xin,   // bf16 [N+1,D]
                        const int* __restrict__ cslab,
                        const unsigned char* __restrict__ ccnt,
                        const unsigned short* __restrict__ wt,    // bf16 [64][128]
                        const float* __restrict__ bl,
                        TOUT* __restrict__ out,
                        int relu) {
    __shared__ __align__(16) unsigned short sA[32][136];  // [row][k: 0-63 mean | 64-127 x]
    __shared__ int raw[RAWCAP];       // compacted packed edges (src<<5 | dlow)
    __shared__ int elist[ELCAP];      // per-row padded src lists
    __shared__ int ehist[BINSZ];
    __shared__ int ecur[BINSZ];
    __shared__ int eoff[BINSZ];
    __shared__ int edeg[BINSZ];
    __shared__ unsigned char ccs[NC + 2];
    __shared__ int etot;

    const uint2* __restrict__ xin64 = (const uint2*)xin;   // row = 16 uint2

    const int tid = threadIdx.x;
    const int b = blockIdx.x;
    const int row0 = b * BINSZ;

    const int wave = tid >> 6;
    const int lane = tid & 63;
    const int q  = lane >> 4;
    const int f2 = lane & 15;

    // ---- mini-build phase ----
    if (tid < BINSZ) ehist[tid] = 0;
    if (tid == 0) etot = 0;
    for (int i = tid; i < NC; i += 256) ccs[i] = ccnt[(size_t)b * NC + i];
    __syncthreads();

    // flat validity-guarded read of this bin's contiguous cells (int4 granularity)
    const int4* __restrict__ cb4 = (const int4*)(cslab + (size_t)b * NC * CAP);
    for (int i = tid; i < NC * CAP / 4; i += 256) {
        int c = i >> 2;              // CAP/4 = 4 int4 per cell
        int rbase = (i & 3) * 4;
        int vc = (int)ccs[c];
        if (rbase < vc) {
            int4 v4 = cb4[i];
            int nv = vc - rbase; if (nv > 4) nv = 4;
            int p = atomicAdd(&etot, nv);
            if (p + nv <= RAWCAP) {
                raw[p] = v4.x;                 atomicAdd(&ehist[v4.x & 31], 1);
                if (nv > 1) { raw[p+1] = v4.y; atomicAdd(&ehist[v4.y & 31], 1); }
                if (nv > 2) { raw[p+2] = v4.z; atomicAdd(&ehist[v4.z & 31], 1); }
                if (nv > 3) { raw[p+3] = v4.w; atomicAdd(&ehist[v4.w & 31], 1); }
            }
        }
    }
    __syncthreads();

    // 32-entry exclusive scan of x4-padded degrees (wave 0, lanes 0..31)
    if (tid < BINSZ) {
        int h = ehist[tid];
        int p = (h + 3) & ~3;
        int v = p;
        for (int off = 1; off < 32; off <<= 1) {
            int u = __shfl_up(v, off);
            if (tid >= off) v += u;
        }
        int excl = v - p;
        eoff[tid] = excl;
        ecur[tid] = excl;
        edeg[tid] = h;
        for (int j = h; j < p; ++j) elist[excl + j] = ZERO_NODE;   // x4 pads
    }
    __syncthreads();

    int etc = etot; if (etc > RAWCAP) etc = RAWCAP;
    for (int i = tid; i < etc; i += 256) {
        int v = raw[i];
        int p = atomicAdd(&ecur[v & 31], 1);
        elist[p] = v >> BSHIFT;
    }
    __syncthreads();

    // ---- gather phase (4 rows per wave iteration, idx from LDS) ----
#pragma unroll
    for (int j = 0; j < 2; ++j) {
        const int rb = wave * 8 + 4 * j;
        int dg0 = edeg[rb + 0], dg1 = edeg[rb + 1];
        int dg2 = edeg[rb + 2], dg3 = edeg[rb + 3];
        int st0 = eoff[rb + 0], st1 = eoff[rb + 1];
        int st2 = eoff[rb + 2], st3 = eoff[rb + 3];
        int pd0 = (dg0 + 3) & ~3, pd1 = (dg1 + 3) & ~3;
        int pd2 = (dg2 + 3) & ~3, pd3 = (dg3 + 3) & ~3;
        int m0 = pd0 > 64 ? 64 : pd0, m1 = pd1 > 64 ? 64 : pd1;
        int m2 = pd2 > 64 ? 64 : pd2, m3 = pd3 > 64 ? 64 : pd3;

        int idx0 = ZERO_NODE, idx1 = ZERO_NODE, idx2 = ZERO_NODE, idx3 = ZERO_NODE;
        if (lane < m0) idx0 = elist[st0 + lane];
        if (lane < m1) idx1 = elist[st1 + lane];
        if (lane < m2) idx2 = elist[st2 + lane];
        if (lane < m3) idx3 = elist[st3 + lane];
        uint2 xr0 = xin64[(size_t)(row0 + rb + 0) * 16 + f2];
        uint2 xr1 = xin64[(size_t)(row0 + rb + 1) * 16 + f2];
        uint2 xr2 = xin64[(size_t)(row0 + rb + 2) * 16 + f2];
        uint2 xr3 = xin64[(size_t)(row0 + rb + 3) * 16 + f2];

        float4 c0 = make_float4(0.f, 0.f, 0.f, 0.f);
        float4 c1 = make_float4(0.f, 0.f, 0.f, 0.f);
        float4 c2 = make_float4(0.f, 0.f, 0.f, 0.f);
        float4 c3 = make_float4(0.f, 0.f, 0.f, 0.f);

        int q0 = m0 >> 2, q1 = m1 >> 2, q2 = m2 >> 2, q3 = m3 >> 2;
        int qa = q0 > q1 ? q0 : q1, qb = q2 > q3 ? q2 : q3;
        int quads = qa > qb ? qa : qb;
        int t = 0;
        for (; t + 2 <= quads; t += 2) {
            // shfl slots past a row's quads hold ZERO_NODE -> zero-row gather
            int e00 = __shfl(idx0, 4 * t + q), e01 = __shfl(idx0, 4 * t + 4 + q);
            int e10 = __shfl(idx1, 4 * t + q), e11 = __shfl(idx1, 4 * t + 4 + q);
            int e20 = __shfl(idx2, 4 * t + q), e21 = __shfl(idx2, 4 * t + 4 + q);
            int e30 = __shfl(idx3, 4 * t + q), e31 = __shfl(idx3, 4 * t + 4 + q);
            uint2 u00 = xin64[(size_t)e00 * 16 + f2];
            uint2 u01 = xin64[(size_t)e01 * 16 + f2];
            uint2 u10 = xin64[(size_t)e10 * 16 + f2];
            uint2 u11 = xin64[(size_t)e11 * 16 + f2];
            uint2 u20 = xin64[(size_t)e20 * 16 + f2];
            uint2 u21 = xin64[(size_t)e21 * 16 + f2];
            uint2 u30 = xin64[(size_t)e30 * 16 + f2];
            uint2 u31 = xin64[(size_t)e31 * 16 + f2];
            acc_bf4(c0, u00); acc_bf4(c0, u01);
            acc_bf4(c1, u10); acc_bf4(c1, u11);
            acc_bf4(c2, u20); acc_bf4(c2, u21);
            acc_bf4(c3, u30); acc_bf4(c3, u31);
        }
        for (; t < quads; ++t) {
            int e00 = __shfl(idx0, 4 * t + q);
            int e10 = __shfl(idx1, 4 * t + q);
            int e20 = __shfl(idx2, 4 * t + q);
            int e30 = __shfl(idx3, 4 * t + q);
            uint2 u00 = xin64[(size_t)e00 * 16 + f2];
            uint2 u10 = xin64[(size_t)e10 * 16 + f2];
            uint2 u20 = xin64[(size_t)e20 * 16 + f2];
            uint2 u30 = xin64[(size_t)e30 * 16 + f2];
            acc_bf4(c0, u00); acc_bf4(c1, u10);
            acc_bf4(c2, u20); acc_bf4(c3, u30);
        }

        // rare slow path: degree > 64 (Poisson(12.5) tail, ~never taken)
        if (__builtin_expect(pd0 > 64, 0)) {
            for (int base = 64; base < pd0; base += 64) {
                int m = pd0 - base; if (m > 64) m = 64;
                int idx = ZERO_NODE;
                if (lane < m) idx = elist[st0 + base + lane];
                int qds = m >> 2;
                for (int tt = 0; tt < qds; ++tt) {
                    int e = __shfl(idx, 4 * tt + q);
                    acc_bf4(c0, xin64[(size_t)e * 16 + f2]);
                }
            }
        }
        if (__builtin_expect(pd1 > 64, 0)) {
            for (int base = 64; base < pd1; base += 64) {
                int m = pd1 - base; if (m > 64) m = 64;
                int idx = ZERO_NODE;
                if (lane < m) idx = elist[st1 + base + lane];
                int qds = m >> 2;
                for (int tt = 0; tt < qds; ++tt) {
                    int e = __shfl(idx, 4 * tt + q);
                    acc_bf4(c1, xin64[(size_t)e * 16 + f2]);
                }
            }
        }
        if (__builtin_expect(pd2 > 64, 0)) {
            for (int base = 64; base < pd2; base += 64) {
                int m = pd2 - base; if (m > 64) m = 64;
                int idx = ZERO_NODE;
                if (lane < m) idx = elist[st2 + base + lane];
                int qds = m >> 2;
                for (int tt = 0; tt < qds; ++tt) {
                    int e = __shfl(idx, 4 * tt + q);
                    acc_bf4(c2, xin64[(size_t)e * 16 + f2]);
                }
            }
        }
        if (__builtin_expect(pd3 > 64, 0)) {
            for (int base = 64; base < pd3; base += 64) {
                int m = pd3 - base; if (m > 64) m = 64;
                int idx = ZERO_NODE;
                if (lane < m) idx = elist[st3 + base + lane];
                int qds = m >> 2;
                for (int tt = 0; tt < qds; ++tt) {
                    int e = __shfl(idx, 4 * tt + q);
                    acc_bf4(c3, xin64[(size_t)e * 16 + f2]);
                }
            }
        }

        c0.x += __shfl_xor(c0.x, 16); c0.y += __shfl_xor(c0.y, 16);
        c0.z += __shfl_xor(c0.z, 16); c0.w += __shfl_xor(c0.w, 16);
        c1.x += __shfl_xor(c1.x, 16); c1.y += __shfl_xor(c1.y, 16);
        c1.z += __shfl_xor(c1.z, 16); c1.w += __shfl_xor(c1.w, 16);
        c2.x += __shfl_xor(c2.x, 16); c2.y += __shfl_xor(c2.y, 16);
        c2.z += __shfl_xor(c2.z, 16); c2.w += __shfl_xor(c2.w, 16);
        c3.x += __shfl_xor(c3.x, 16); c3.y += __shfl_xor(c3.y, 16);
        c3.z += __shfl_xor(c3.z, 16); c3.w += __shfl_xor(c3.w, 16);
        c0.x += __shfl_xor(c0.x, 32); c0.y += __shfl_xor(c0.y, 32);
        c0.z += __shfl_xor(c0.z, 32); c0.w += __shfl_xor(c0.w, 32);
        c1.x += __shfl_xor(c1.x, 32); c1.y += __shfl_xor(c1.y, 32);
        c1.z += __shfl_xor(c1.z, 32); c1.w += __shfl_xor(c1.w, 32);
        c2.x += __shfl_xor(c2.x, 32); c2.y += __shfl_xor(c2.y, 32);
        c2.z += __shfl_xor(c2.z, 32); c2.w += __shfl_xor(c2.w, 32);
        c3.x += __shfl_xor(c3.x, 32); c3.y += __shfl_xor(c3.y, 32);
        c3.z += __shfl_xor(c3.z, 32); c3.w += __shfl_xor(c3.w, 32);

        float i0 = 1.0f / (float)(dg0 > 0 ? dg0 : 1);
        float i1 = 1.0f / (float)(dg1 > 0 ? dg1 : 1);
        float i2 = 1.0f / (float)(dg2 > 0 ? dg2 : 1);
        float i3 = 1.0f / (float)(dg3 > 0 ? dg3 : 1);
        if (q == 0) {
            unsigned int p0, p1;
            p0 = (unsigned int)f2bf(c0.x * i0) | ((unsigned int)f2bf(c0.y * i0) << 16);
            p1 = (unsigned int)f2bf(c0.z * i0) | ((unsigned int)f2bf(c0.w * i0) << 16);
            *(uint2*)&sA[rb + 0][f2 * 4] = make_uint2(p0, p1);
            *(uint2*)&sA[rb + 0][64 + f2 * 4] = xr0;
            p0 = (unsigned int)f2bf(c1.x * i1) | ((unsigned int)f2bf(c1.y * i1) << 16);
            p1 = (unsigned int)f2bf(c1.z * i1) | ((unsigned int)f2bf(c1.w * i1) << 16);
            *(uint2*)&sA[rb + 1][f2 * 4] = make_uint2(p0, p1);
            *(uint2*)&sA[rb + 1][64 + f2 * 4] = xr1;
            p0 = (unsigned int)f2bf(c2.x * i2) | ((unsigned int)f2bf(c2.y * i2) << 16);
            p1 = (unsigned int)f2bf(c2.z * i2) | ((unsigned int)f2bf(c2.w * i2) << 16);
            *(uint2*)&sA[rb + 2][f2 * 4] = make_uint2(p0, p1);
            *(uint2*)&sA[rb + 2][64 + f2 * 4] = xr2;
            p0 = (unsigned int)f2bf(c3.x * i3) | ((unsigned int)f2bf(c3.y * i3) << 16);
            p1 = (unsigned int)f2bf(c3.z * i3) | ((unsigned int)f2bf(c3.w * i3) << 16);
            *(uint2*)&sA[rb + 3][f2 * 4] = make_uint2(p0, p1);
            *(uint2*)&sA[rb + 3][64 + f2 * 4] = xr3;
        }
    }
    __syncthreads();

    // ---- MFMA GEMM phase ----
    const int tm = wave & 1;                 // tile row (0..1)
    const int tn0 = (wave >> 1) * 2;         // first tile col of this wave
    const int mrow = tm * 16 + (lane & 15);  // A row for this lane
    const int kq = (lane >> 4) * 8;          // k sub-offset within 32-chunk

    short8 afr[4];
#pragma unroll
    for (int kk = 0; kk < 4; ++kk)
        afr[kk] = *(const short8*)&sA[mrow][kk * 32 + kq];

#pragma unroll
    for (int ti = 0; ti < 2; ++ti) {
        const int tn = tn0 + ti;
        const int col = tn * 16 + (lane & 15);
        float bias = bl[col];
        f32x4 acc = {bias, bias, bias, bias};
#pragma unroll
        for (int kk = 0; kk < 4; ++kk) {
            short8 bfr = *(const short8*)&wt[col * 128 + kk * 32 + kq];
            acc = __builtin_amdgcn_mfma_f32_16x16x32_bf16(afr[kk], bfr, acc, 0, 0, 0);
        }
        const int r0 = row0 + tm * 16 + (lane >> 4) * 4;
#pragma unroll
        for (int reg = 0; reg < 4; ++reg) {
            float o = relu ? fmaxf(acc[reg], 0.f) : acc[reg];
            if constexpr (__hip_internal::is_same<TOUT, unsigned short>::value)
                out[(size_t)(r0 + reg) * D + col] = f2bf(o);
            else
                out[(size_t)(r0 + reg) * D + col] = o;
        }
    }
}

extern "C" void kernel_launch(void* const* d_in, const int* in_sizes, int n_in,
                              void* d_out, int out_size, void* d_ws, size_t ws_size,
                              hipStream_t stream) {
    const float* x   = (const float*)d_in[0];
    const int*   ei  = (const int*)d_in[1];
    const float* Wl1 = (const float*)d_in[2];
    const float* b1  = (const float*)d_in[3];
    const float* Wr1 = (const float*)d_in[4];
    const float* Wl2 = (const float*)d_in[5];
    const float* b2  = (const float*)d_in[6];
    const float* Wr2 = (const float*)d_in[7];

    const int* src = ei;
    const int* dst = ei + N_EDGES;

    // ws layout, ~75 MB of the 256 MB workspace:
    //   cslab[3125][306][16] ints (61.2 MB) | ccnt[3125][306] u8 (0.96 MB) |
    //   wt[2][64][128] bf16 (32 KB) | h bf16 [N+1][64] (12.8 MB)
    int* cslab = (int*)d_ws;                                   // 15,300,000 ints
    unsigned char* ccnt = (unsigned char*)(cslab + (size_t)NBIN * NC * CAP);
    size_t ccnt_bytes = ((size_t)NBIN * NC + 3) & ~(size_t)3;  // pad to 4B
    unsigned short* wt_all = (unsigned short*)(ccnt + ccnt_bytes);   // 16384 ushorts
    unsigned short* wt1 = wt_all;
    unsigned short* wt2 = wt_all + 64 * 128;
    unsigned short* h = wt_all + 2 * 64 * 128;   // [N+1, D] bf16
    float* out = (float*)d_out;
    unsigned short* xb = (unsigned short*)d_out;  // bf16 x scratch in d_out [N+1, D]

    part_convert_kernel<<<NC, 1024, 0, stream>>>(
        (const float4*)x, (ushort4*)xb,
        (unsigned int*)(xb + (size_t)ZERO_NODE * D),
        (unsigned int*)(h + (size_t)ZERO_NODE * D),
        Wl1, Wr1, Wl2, Wr2, wt_all,
        src, dst, cslab, ccnt);

    fused_layer_kernel<unsigned short><<<NBIN, 256, 0, stream>>>(
        xb, cslab, ccnt, wt1, b1, h, /*relu=*/1);
    fused_layer_kernel<float><<<NBIN, 256, 0, stream>>>(
        h, cslab, ccnt, wt2, b2, out, /*relu=*/0);
}

// Round 13
// 198.416 us; speedup vs baseline: 1.1451x; 1.1451x over previous
//
#include <hip/hip_runtime.h>

#define N_NODES 100000
#define N_EDGES 1250000
#define D 64
#define ZERO_NODE N_NODES       // virtual all-zero row for padding

#define BIN_SHIFT 8
#define BIN_NODES 256
#define NBINS ((N_NODES + BIN_NODES - 1) >> BIN_SHIFT)   // 391
#define BIN_CAP 3712            // per-bin edge cap: mean 3197, sigma ~57 -> ~9 sigma
#define BIN_SLAB (BIN_CAP + 3 * BIN_NODES)               // 4480: worst-case padded bin
#define CHUNK 2048              // edges per partition block -> 611 blocks
#define NCHUNK ((N_EDGES + CHUNK - 1) / CHUNK)           // 611
#define CCAP 32                 // per-(chunk,bin) slot cap; Poisson(5.24), P(>32)~1e-9
#define CONV4 (N_NODES * D / 4) // 1,600,000 float4s to convert

// final CSR slab: per-bin fixed regions of BIN_SLAB ints
#define SLAB_INTS (NBINS * BIN_SLAB)    // 1,751,680

typedef __attribute__((ext_vector_type(8))) short short8;   // 8 bf16 (4 VGPRs)
typedef __attribute__((ext_vector_type(4))) float f32x4;    // MFMA acc

// ---- bf16 helpers (finite values only) ----
__device__ inline unsigned short f2bf(float f) {
    unsigned int u = __float_as_uint(f);
    unsigned int r = (u + 0x7fffu + ((u >> 16) & 1u)) >> 16;
    return (unsigned short)r;
}
__device__ inline void acc_bf4(float4& c, uint2 u) {
    c.x += __uint_as_float(u.x << 16);
    c.y += __uint_as_float(u.x & 0xffff0000u);
    c.z += __uint_as_float(u.y << 16);
    c.w += __uint_as_float(u.y & 0xffff0000u);
}

// ---- pass 1 (merged convert + partition): deterministic per-(chunk,bin) slots ----
// 611 blocks x 1024 threads. Single pass over the chunk's edges: rank from a
// block-local LDS cursor, edge stored straight to cslab[chunk][bin][rank]
// ([chunk][bin] layout: write side compact per chunk -- r11 measured that
// transposing to [bin][chunk] just moves the scatter to the write side, -5us).
// NO global atomics. Convert (fp32->bf16), zero-row init, wt transpose ride along.
__global__ __launch_bounds__(1024)
void part_convert_kernel(const float4* __restrict__ xin, ushort4* __restrict__ xb,
                         unsigned int* __restrict__ xb_zrow,
                         unsigned int* __restrict__ h_zrow,
                         const float* __restrict__ Wl1, const float* __restrict__ Wr1,
                         const float* __restrict__ Wl2, const float* __restrict__ Wr2,
                         unsigned short* __restrict__ wt,
                         const int* __restrict__ src, const int* __restrict__ dst,
                         int* __restrict__ cslab, unsigned short* __restrict__ ccnt) {
    __shared__ int lcur[NBINS];

    const int t = threadIdx.x;
    const int c = blockIdx.x;
    if (t < NBINS) lcur[t] = 0;

    // convert x fp32 -> bf16 (grid-stride) + one-time extras
    const int g0 = c * 1024 + t;
    const int gsz = NCHUNK * 1024;   // 625,664
    for (int g = g0; g < CONV4; g += gsz) {
        float4 v = xin[g];
        ushort4 u;
        u.x = f2bf(v.x); u.y = f2bf(v.y); u.z = f2bf(v.z); u.w = f2bf(v.w);
        xb[g] = u;
    }
    if (g0 < 32) { xb_zrow[g0] = 0u; h_zrow[g0] = 0u; }   // 64 bf16 = 32 uints each
    if (g0 < 2 * 64 * 128) {
        int layer = g0 >> 13;
        int n = (g0 >> 7) & 63;
        int k = g0 & 127;
        const float* W = layer ? (k < 64 ? Wl2 : Wr2) : (k < 64 ? Wl1 : Wr1);
        wt[g0] = f2bf(W[(k & 63) * D + n]);
    }
    __syncthreads();

    const int e0 = c * CHUNK;
    int cnt = N_EDGES - e0; if (cnt > CHUNK) cnt = CHUNK;
    for (int i = t; i < cnt; i += 1024) {
        int d = dst[e0 + i];
        int s = src[e0 + i];
        int b = d >> BIN_SHIFT;
        int r = atomicAdd(&lcur[b], 1);
        if (r < CCAP)
            cslab[(c * NBINS + b) * CCAP + r] = (s << BIN_SHIFT) | (d & (BIN_NODES - 1));
    }
    __syncthreads();

    if (t < NBINS) {
        int v = lcur[t];
        ccnt[t * NCHUNK + c] = (unsigned short)(v < CCAP ? v : CCAP);   // [bin][chunk]
    }
}

// ---- pass 2: per-bin build: count-scan + LDS stage + hist + CSR emit ----
// 391 blocks x 1024 threads. Reads the bin's 611 chunk-counts (contiguous),
// scans them, gathers the runs into LDS stage[] via int4-wide reads (the
// (chunk,bin) region is 128B-aligned; mean run 5.24 ints -> 2 int4 loads vs
// ~6 scalar), then hist -> padded scan -> deg/rstart/ZERO pads -> scatter,
// all LDS-resident. CSR contract unchanged.
__global__ __launch_bounds__(1024)
void build_kernel(const int* __restrict__ cslab, const unsigned short* __restrict__ ccnt,
                  int* __restrict__ deg_out, int* __restrict__ rstart_out,
                  int* __restrict__ slabs) {
    __shared__ int soff[NCHUNK];      // scanned chunk offsets (611)
    __shared__ int scnt[NCHUNK];      // chunk counts
    __shared__ int stage[BIN_CAP];    // staged packed edges (src<<8 | dlow)
    __shared__ int hist[BIN_NODES];
    __shared__ int cur[BIN_NODES];
    __shared__ int wsum[16];
    __shared__ int wsum2[16];
    __shared__ int tot_s;

    const int b = blockIdx.x;
    const int t = threadIdx.x;
    const int lane = t & 63, wave = t >> 6;   // 16 waves
    const int nb0 = b << BIN_SHIFT;

    // scan of 611 chunk counts (wave shuffle scan + wave-sum combine)
    int v = (t < NCHUNK) ? (int)ccnt[b * NCHUNK + t] : 0;
    int sv = v;
    for (int off = 1; off < 64; off <<= 1) {
        int u = __shfl_up(sv, off);
        if (lane >= off) sv += u;
    }
    if (lane == 63) wsum[wave] = sv;
    if (t < BIN_NODES) hist[t] = 0;
    __syncthreads();
    int wpre = 0;
    for (int w = 0; w < wave; ++w) wpre += wsum[w];
    int excl = sv + wpre - v;
    if (t < NCHUNK) { soff[t] = excl; scnt[t] = v; }
    if (t == NCHUNK - 1) tot_s = excl + v;
    __syncthreads();

    int cntb = tot_s; if (cntb > BIN_CAP) cntb = BIN_CAP;

    // stage: thread t copies chunk t's run into packed LDS positions (int4-wide)
    if (t < NCHUNK) {
        int base = soff[t], n = scnt[t];
        const int4* __restrict__ p4 =
            (const int4*)&cslab[(t * NBINS + b) * CCAP];   // 128B-aligned region
        int n4 = (n + 3) >> 2;
        for (int r4 = 0; r4 < n4; ++r4) {
            int4 w4 = p4[r4];
            int r = r4 * 4;
            int pos = base + r;
            if (r < n && pos < BIN_CAP) stage[pos] = w4.x;
            if (r + 1 < n && pos + 1 < BIN_CAP) stage[pos + 1] = w4.y;
            if (r + 2 < n && pos + 2 < BIN_CAP) stage[pos + 2] = w4.z;
            if (r + 3 < n && pos + 3 < BIN_CAP) stage[pos + 3] = w4.w;
        }
    }
    __syncthreads();

    // per-node histogram from LDS stage
    for (int i = t; i < cntb; i += 1024)
        atomicAdd(&hist[stage[i] & (BIN_NODES - 1)], 1);
    __syncthreads();

    // exclusive scan of 256 x4-padded degrees
    int h = (t < BIN_NODES) ? hist[t] : 0;
    int p = (h + 3) & ~3;
    int s2 = p;
    for (int off = 1; off < 64; off <<= 1) {
        int u = __shfl_up(s2, off);
        if (lane >= off) s2 += u;
    }
    if (lane == 63) wsum2[wave] = s2;
    __syncthreads();
    int wpre2 = 0;
    for (int w = 0; w < wave; ++w) wpre2 += wsum2[w];
    if (t < BIN_NODES) {
        int excl2 = s2 + wpre2 - p;        // sum(padded) <= BIN_CAP + 3*256 = BIN_SLAB
        int rs = b * BIN_SLAB + excl2;
        cur[t] = rs;
        int n = nb0 + t;
        if (n < N_NODES) {
            deg_out[n] = h;
            rstart_out[n] = rs;
            for (int j = h; j < p; ++j) slabs[rs + j] = ZERO_NODE;
        }
    }
    __syncthreads();

    // scatter LDS stage -> final padded CSR (dense per-bin window)
    for (int i = t; i < cntb; i += 1024) {
        int pk = stage[i];
        int pos = atomicAdd(&cur[pk & (BIN_NODES - 1)], 1);
        slabs[pos] = pk >> BIN_SHIFT;
    }
}

// ---------------- fused layer: gather-mean + MFMA GEMM ----------------
// Gather: quad-edge (uint2/lane, 16 lanes/row), FOUR rows per wave iteration.
// launch_bounds(256,6): 85-VGPR budget, no spill (VGPR=40 measured r10).
// NOTE (r9/r10 measured): gather is L2-miss/L3-path saturated at ~44.5us --
// MLP depth and occupancy are both saturated levers; do not touch.
// NOTE (r12 measured): in-kernel mini-build costs +15us/layer -- keep the
// two-pass CSR build (amortized over both layers).
// GEMM: C[32,64] = [mean|x]_bf16[32,128] @ wt[128,64] + b  via
// mfma_f32_16x16x32_bf16 (8 tiles, 4 waves x 2 tiles x 4 K-steps).
// sA = bf16 [32][136] (8.7 KB LDS).
template <typename TOUT>
__global__ __launch_bounds__(256, 6)
void fused_layer_kernel(const unsigned short* __restrict__ xin,   // bf16 [N+1,D]
                        const int* __restrict__ rstart,
                        const int* __restrict__ deg,
                        const int* __restrict__ sorted_src,
                        const unsigned short* __restrict__ wt,    // bf16 [64][128]
                        const float* __restrict__ bl,
                        TOUT* __restrict__ out,
                        int relu) {
    __shared__ __align__(16) unsigned short sA[32][136];   // [row][k: 0-63 mean | 64-127 x]

    const uint2* __restrict__ xin64 = (const uint2*)xin;   // row = 16 uint2

    const int tid = threadIdx.x;
    const int row0 = blockIdx.x * 32;

    const int wave = tid >> 6;
    const int lane = tid & 63;
    const int q  = lane >> 4;
    const int f2 = lane & 15;

#pragma unroll
    for (int j = 0; j < 2; ++j) {
        const int rb = wave * 8 + 4 * j;
        const int n0 = row0 + rb, n1 = n0 + 1, n2 = n0 + 2, n3 = n0 + 3;

        int dg0 = deg[n0], dg1 = deg[n1], dg2 = deg[n2], dg3 = deg[n3];
        int st0 = rstart[n0], st1 = rstart[n1], st2 = rstart[n2], st3 = rstart[n3];
        int pd0 = (dg0 + 3) & ~3, pd1 = (dg1 + 3) & ~3;
        int pd2 = (dg2 + 3) & ~3, pd3 = (dg3 + 3) & ~3;
        int m0 = pd0 > 64 ? 64 : pd0, m1 = pd1 > 64 ? 64 : pd1;
        int m2 = pd2 > 64 ? 64 : pd2, m3 = pd3 > 64 ? 64 : pd3;

        int idx0 = ZERO_NODE, idx1 = ZERO_NODE, idx2 = ZERO_NODE, idx3 = ZERO_NODE;
        if (lane < m0) idx0 = sorted_src[st0 + lane];
        if (lane < m1) idx1 = sorted_src[st1 + lane];
        if (lane < m2) idx2 = sorted_src[st2 + lane];
        if (lane < m3) idx3 = sorted_src[st3 + lane];
        uint2 xr0 = xin64[(size_t)n0 * 16 + f2];
        uint2 xr1 = xin64[(size_t)n1 * 16 + f2];
        uint2 xr2 = xin64[(size_t)n2 * 16 + f2];
        uint2 xr3 = xin64[(size_t)n3 * 16 + f2];

        float4 c0 = make_float4(0.f, 0.f, 0.f, 0.f);
        float4 c1 = make_float4(0.f, 0.f, 0.f, 0.f);
        float4 c2 = make_float4(0.f, 0.f, 0.f, 0.f);
        float4 c3 = make_float4(0.f, 0.f, 0.f, 0.f);

        int q0 = m0 >> 2, q1 = m1 >> 2, q2 = m2 >> 2, q3 = m3 >> 2;
        int qa = q0 > q1 ? q0 : q1, qb = q2 > q3 ? q2 : q3;
        int quads = qa > qb ? qa : qb;
        int t = 0;
        for (; t + 2 <= quads; t += 2) {
            // shfl slots past a row's quads hold ZERO_NODE -> zero-row gather
            int e00 = __shfl(idx0, 4 * t + q), e01 = __shfl(idx0, 4 * t + 4 + q);
            int e10 = __shfl(idx1, 4 * t + q), e11 = __shfl(idx1, 4 * t + 4 + q);
            int e20 = __shfl(idx2, 4 * t + q), e21 = __shfl(idx2, 4 * t + 4 + q);
            int e30 = __shfl(idx3, 4 * t + q), e31 = __shfl(idx3, 4 * t + 4 + q);
            uint2 u00 = xin64[(size_t)e00 * 16 + f2];
            uint2 u01 = xin64[(size_t)e01 * 16 + f2];
            uint2 u10 = xin64[(size_t)e10 * 16 + f2];
            uint2 u11 = xin64[(size_t)e11 * 16 + f2];
            uint2 u20 = xin64[(size_t)e20 * 16 + f2];
            uint2 u21 = xin64[(size_t)e21 * 16 + f2];
            uint2 u30 = xin64[(size_t)e30 * 16 + f2];
            uint2 u31 = xin64[(size_t)e31 * 16 + f2];
            acc_bf4(c0, u00); acc_bf4(c0, u01);
            acc_bf4(c1, u10); acc_bf4(c1, u11);
            acc_bf4(c2, u20); acc_bf4(c2, u21);
            acc_bf4(c3, u30); acc_bf4(c3, u31);
        }
        for (; t < quads; ++t) {
            int e00 = __shfl(idx0, 4 * t + q);
            int e10 = __shfl(idx1, 4 * t + q);
            int e20 = __shfl(idx2, 4 * t + q);
            int e30 = __shfl(idx3, 4 * t + q);
            uint2 u00 = xin64[(size_t)e00 * 16 + f2];
            uint2 u10 = xin64[(size_t)e10 * 16 + f2];
            uint2 u20 = xin64[(size_t)e20 * 16 + f2];
            uint2 u30 = xin64[(size_t)e30 * 16 + f2];
            acc_bf4(c0, u00); acc_bf4(c1, u10);
            acc_bf4(c2, u20); acc_bf4(c3, u30);
        }

        // rare slow path: degree > 64 (Poisson(12.5) tail, ~never taken).
        // Unrolled per-row -- NO runtime-indexed arrays (they force scratch).
        if (__builtin_expect(pd0 > 64, 0)) {
            for (int base = 64; base < pd0; base += 64) {
                int m = pd0 - base; if (m > 64) m = 64;
                int idx = ZERO_NODE;
                if (lane < m) idx = sorted_src[st0 + base + lane];
                int qds = m >> 2;
                for (int tt = 0; tt < qds; ++tt) {
                    int e = __shfl(idx, 4 * tt + q);
                    acc_bf4(c0, xin64[(size_t)e * 16 + f2]);
                }
            }
        }
        if (__builtin_expect(pd1 > 64, 0)) {
            for (int base = 64; base < pd1; base += 64) {
                int m = pd1 - base; if (m > 64) m = 64;
                int idx = ZERO_NODE;
                if (lane < m) idx = sorted_src[st1 + base + lane];
                int qds = m >> 2;
                for (int tt = 0; tt < qds; ++tt) {
                    int e = __shfl(idx, 4 * tt + q);
                    acc_bf4(c1, xin64[(size_t)e * 16 + f2]);
                }
            }
        }
        if (__builtin_expect(pd2 > 64, 0)) {
            for (int base = 64; base < pd2; base += 64) {
                int m = pd2 - base; if (m > 64) m = 64;
                int idx = ZERO_NODE;
                if (lane < m) idx = sorted_src[st2 + base + lane];
                int qds = m >> 2;
                for (int tt = 0; tt < qds; ++tt) {
                    int e = __shfl(idx, 4 * tt + q);
                    acc_bf4(c2, xin64[(size_t)e * 16 + f2]);
                }
            }
        }
        if (__builtin_expect(pd3 > 64, 0)) {
            for (int base = 64; base < pd3; base += 64) {
                int m = pd3 - base; if (m > 64) m = 64;
                int idx = ZERO_NODE;
                if (lane < m) idx = sorted_src[st3 + base + lane];
                int qds = m >> 2;
                for (int tt = 0; tt < qds; ++tt) {
                    int e = __shfl(idx, 4 * tt + q);
                    acc_bf4(c3, xin64[(size_t)e * 16 + f2]);
                }
            }
        }

        c0.x += __shfl_xor(c0.x, 16); c0.y += __shfl_xor(c0.y, 16);
        c0.z += __shfl_xor(c0.z, 16); c0.w += __shfl_xor(c0.w, 16);
        c1.x += __shfl_xor(c1.x, 16); c1.y += __shfl_xor(c1.y, 16);
        c1.z += __shfl_xor(c1.z, 16); c1.w += __shfl_xor(c1.w, 16);
        c2.x += __shfl_xor(c2.x, 16); c2.y += __shfl_xor(c2.y, 16);
        c2.z += __shfl_xor(c2.z, 16); c2.w += __shfl_xor(c2.w, 16);
        c3.x += __shfl_xor(c3.x, 16); c3.y += __shfl_xor(c3.y, 16);
        c3.z += __shfl_xor(c3.z, 16); c3.w += __shfl_xor(c3.w, 16);
        c0.x += __shfl_xor(c0.x, 32); c0.y += __shfl_xor(c0.y, 32);
        c0.z += __shfl_xor(c0.z, 32); c0.w += __shfl_xor(c0.w, 32);
        c1.x += __shfl_xor(c1.x, 32); c1.y += __shfl_xor(c1.y, 32);
        c1.z += __shfl_xor(c1.z, 32); c1.w += __shfl_xor(c1.w, 32);
        c2.x += __shfl_xor(c2.x, 32); c2.y += __shfl_xor(c2.y, 32);
        c2.z += __shfl_xor(c2.z, 32); c2.w += __shfl_xor(c2.w, 32);
        c3.x += __shfl_xor(c3.x, 32); c3.y += __shfl_xor(c3.y, 32);
        c3.z += __shfl_xor(c3.z, 32); c3.w += __shfl_xor(c3.w, 32);

        float i0 = 1.0f / (float)(dg0 > 0 ? dg0 : 1);
        float i1 = 1.0f / (float)(dg1 > 0 ? dg1 : 1);
        float i2 = 1.0f / (float)(dg2 > 0 ? dg2 : 1);
        float i3 = 1.0f / (float)(dg3 > 0 ? dg3 : 1);
        if (q == 0) {
            unsigned int p0, p1;
            p0 = (unsigned int)f2bf(c0.x * i0) | ((unsigned int)f2bf(c0.y * i0) << 16);
            p1 = (unsigned int)f2bf(c0.z * i0) | ((unsigned int)f2bf(c0.w * i0) << 16);
            *(uint2*)&sA[rb + 0][f2 * 4] = make_uint2(p0, p1);
            *(uint2*)&sA[rb + 0][64 + f2 * 4] = xr0;
            p0 = (unsigned int)f2bf(c1.x * i1) | ((unsigned int)f2bf(c1.y * i1) << 16);
            p1 = (unsigned int)f2bf(c1.z * i1) | ((unsigned int)f2bf(c1.w * i1) << 16);
            *(uint2*)&sA[rb + 1][f2 * 4] = make_uint2(p0, p1);
            *(uint2*)&sA[rb + 1][64 + f2 * 4] = xr1;
            p0 = (unsigned int)f2bf(c2.x * i2) | ((unsigned int)f2bf(c2.y * i2) << 16);
            p1 = (unsigned int)f2bf(c2.z * i2) | ((unsigned int)f2bf(c2.w * i2) << 16);
            *(uint2*)&sA[rb + 2][f2 * 4] = make_uint2(p0, p1);
            *(uint2*)&sA[rb + 2][64 + f2 * 4] = xr2;
            p0 = (unsigned int)f2bf(c3.x * i3) | ((unsigned int)f2bf(c3.y * i3) << 16);
            p1 = (unsigned int)f2bf(c3.z * i3) | ((unsigned int)f2bf(c3.w * i3) << 16);
            *(uint2*)&sA[rb + 3][f2 * 4] = make_uint2(p0, p1);
            *(uint2*)&sA[rb + 3][64 + f2 * 4] = xr3;
        }
    }
    __syncthreads();

    // ---- MFMA GEMM phase ----
    const int tm = wave & 1;                 // tile row (0..1)
    const int tn0 = (wave >> 1) * 2;         // first tile col of this wave
    const int mrow = tm * 16 + (lane & 15);  // A row for this lane
    const int kq = (lane >> 4) * 8;          // k sub-offset within 32-chunk

    short8 afr[4];
#pragma unroll
    for (int kk = 0; kk < 4; ++kk)
        afr[kk] = *(const short8*)&sA[mrow][kk * 32 + kq];

#pragma unroll
    for (int ti = 0; ti < 2; ++ti) {
        const int tn = tn0 + ti;
        const int col = tn * 16 + (lane & 15);
        float bias = bl[col];
        f32x4 acc = {bias, bias, bias, bias};
#pragma unroll
        for (int kk = 0; kk < 4; ++kk) {
            short8 bfr = *(const short8*)&wt[col * 128 + kk * 32 + kq];
            acc = __builtin_amdgcn_mfma_f32_16x16x32_bf16(afr[kk], bfr, acc, 0, 0, 0);
        }
        const int r0 = row0 + tm * 16 + (lane >> 4) * 4;
#pragma unroll
        for (int reg = 0; reg < 4; ++reg) {
            float o = relu ? fmaxf(acc[reg], 0.f) : acc[reg];
            if constexpr (__hip_internal::is_same<TOUT, unsigned short>::value)
                out[(size_t)(r0 + reg) * D + col] = f2bf(o);
            else
                out[(size_t)(r0 + reg) * D + col] = o;
        }
    }
}

extern "C" void kernel_launch(void* const* d_in, const int* in_sizes, int n_in,
                              void* d_out, int out_size, void* d_ws, size_t ws_size,
                              hipStream_t stream) {
    const float* x   = (const float*)d_in[0];
    const int*   ei  = (const int*)d_in[1];
    const float* Wl1 = (const float*)d_in[2];
    const float* b1  = (const float*)d_in[3];
    const float* Wr1 = (const float*)d_in[4];
    const float* Wl2 = (const float*)d_in[5];
    const float* b2  = (const float*)d_in[6];
    const float* Wr2 = (const float*)d_in[7];

    const int* src = ei;
    const int* dst = ei + N_EDGES;

    // ws layout (ints), ~52 MB of the 256 MB workspace:
    //   cslab[611][391][32] | ccnt[391][611] u16 (120000 ints) | deg[N] | rstart[N]
    //   | slabs[391*4480] | wt[2][64][128] bf16 (8192 ints) | h_bf16[(N+1)*D]
    int* cslab = (int*)d_ws;                                  // 7,644,832 ints
    unsigned short* ccnt = (unsigned short*)(cslab + NCHUNK * NBINS * CCAP);
    int* deg    = cslab + NCHUNK * NBINS * CCAP + 120000;
    int* rstart = deg + N_NODES;
    int* slabs  = rstart + N_NODES;
    unsigned short* wt_all = (unsigned short*)(slabs + SLAB_INTS);   // 16384 ushorts
    unsigned short* wt1 = wt_all;
    unsigned short* wt2 = wt_all + 64 * 128;
    unsigned short* h = wt_all + 2 * 64 * 128;   // [N+1, D] bf16
    float* out = (float*)d_out;
    unsigned short* xb = (unsigned short*)d_out;  // bf16 x scratch in d_out [N+1, D]

    const int dense_blocks = N_NODES / 32;   // 3125

    part_convert_kernel<<<NCHUNK, 1024, 0, stream>>>(
        (const float4*)x, (ushort4*)xb,
        (unsigned int*)(xb + (size_t)ZERO_NODE * D),
        (unsigned int*)(h + (size_t)ZERO_NODE * D),
        Wl1, Wr1, Wl2, Wr2, wt_all,
        src, dst, cslab, ccnt);

    build_kernel<<<NBINS, 1024, 0, stream>>>(cslab, ccnt, deg, rstart, slabs);

    fused_layer_kernel<unsigned short><<<dense_blocks, 256, 0, stream>>>(
        xb, rstart, deg, slabs, wt1, b1, h, /*relu=*/1);
    fused_layer_kernel<float><<<dense_blocks, 256, 0, stream>>>(
        h, rstart, deg, slabs, wt2, b2, out, /*relu=*/0);
}